// Round 1
// baseline (144.962 us; speedup 1.0000x reference)
//
#include <hip/hip_runtime.h>
#include <hip/hip_bf16.h>

typedef __attribute__((ext_vector_type(8))) __bf16 bf16x8;
typedef __attribute__((ext_vector_type(4))) __bf16 bf16x4;
typedef __attribute__((ext_vector_type(4))) float f32x4;

#define DIN 1024
#define DOUT 1024
#define BB 4
#define SS 4096
#define MROWS (BB*SS)   /* 16384 */
#define POOLN 5
#define RR 8
#define NTASKS 5
#define TOPKK 3

// ---------------- K1: colsum + f32->bf16 convert ----------------
// 512 blocks x 256 threads, 32 rows/block, thread t owns cols 4t..4t+3
__global__ __launch_bounds__(256) void k1_colsum_cvt(const float* __restrict__ in,
                                                     __bf16* __restrict__ inB,
                                                     float* __restrict__ colsum) {
    const int t  = threadIdx.x;
    const int r0 = blockIdx.x * 32;
    const int c0 = t * 4;
    float s0 = 0.f, s1 = 0.f, s2 = 0.f, s3 = 0.f;
#pragma unroll 4
    for (int r = r0; r < r0 + 32; ++r) {
        const float4 v = *(const float4*)&in[(size_t)r * DIN + c0];
        s0 += v.x; s1 += v.y; s2 += v.z; s3 += v.w;
        bf16x4 b = { (__bf16)v.x, (__bf16)v.y, (__bf16)v.z, (__bf16)v.w };
        *(bf16x4*)&inB[(size_t)r * DIN + c0] = b;
    }
    atomicAdd(&colsum[c0 + 0], s0);
    atomicAdd(&colsum[c0 + 1], s1);
    atomicAdd(&colsum[c0 + 2], s2);
    atomicAdd(&colsum[c0 + 3], s3);
}

// ---------------- K2: omegas -> top-k -> softmax gate ----------------
__global__ void k2_gate(const float* __restrict__ colsum,
                        const float* __restrict__ lroute,
                        const int* __restrict__ task_id_p,
                        float* __restrict__ gate, int* __restrict__ gidx) {
    const int l = threadIdx.x;  // 64 lanes
    float part[POOLN] = {0.f, 0.f, 0.f, 0.f, 0.f};
    for (int d = l; d < DIN; d += 64) {
        const float cs = colsum[d] * (1.0f / (float)MROWS);
        const float* rp = &lroute[(size_t)1 * DIN * POOLN + (size_t)d * POOLN];
#pragma unroll
        for (int p = 0; p < POOLN; ++p) part[p] += cs * rp[p];
    }
#pragma unroll
    for (int p = 0; p < POOLN; ++p) {
        float v = part[p];
        for (int off = 32; off; off >>= 1) v += __shfl_down(v, off);
        part[p] = v;
    }
    if (l == 0) {
        int tid = *task_id_p;
        if (tid > NTASKS) tid = NTASKS;
        int L = tid < (POOLN - 1) ? tid : (POOLN - 1);   // slice [1:tid+1] clamps
        int k = tid < TOPKK ? tid : TOPKK;
        float sl[POOLN];
        for (int j = 0; j < L; ++j) sl[j] = part[1 + j];
        float G[TOPKK]; int I[TOPKK];
        int used = 0;
        for (int j = 0; j < k; ++j) {
            int best = -1; float bv = 0.f;
            for (int i2 = 0; i2 < L; ++i2) {
                if (used & (1 << i2)) continue;
                if (best < 0 || sl[i2] > bv) { bv = sl[i2]; best = i2; }
            }
            used |= 1 << best; G[j] = bv; I[j] = best;
        }
        if (k > 0) {
            float m = G[0];           // descending -> max first
            float e[TOPKK]; float se = 0.f;
            for (int j = 0; j < k; ++j) { e[j] = expf(G[j] - m); se += e[j]; }
            for (int j = 0; j < k; ++j) { gate[j] = e[j] / se; gidx[j] = I[j]; }
        }
        for (int j = k; j < TOPKK; ++j) { gate[j] = 0.f; gidx[j] = 0; }
    }
}

// ---------------- K3: build two bf16 B^T weight matrices ----------------
// Wb0[o][d] = bf16(W[o][d]);  Wb1[o][d] = bf16(W[o][d] + Dw[d][o])
// Dw[d][o] = sum_j gate_j * sum_r down[I_j][d][r] * up[I_j][r][o]
__global__ __launch_bounds__(256) void k3_weights(const float* __restrict__ W,
                                                  const float* __restrict__ ldown,
                                                  const float* __restrict__ lup,
                                                  const float* __restrict__ gate,
                                                  const int* __restrict__ gidx,
                                                  __bf16* __restrict__ Wb0,
                                                  __bf16* __restrict__ Wb1) {
    const int o = blockIdx.x;
    const int t = threadIdx.x;
    float c[TOPKK][RR];
#pragma unroll
    for (int j = 0; j < TOPKK; ++j) {
        const float g = gate[j];
        const int   p = gidx[j];
#pragma unroll
        for (int r = 0; r < RR; ++r)
            c[j][r] = g * lup[(size_t)p * RR * DOUT + (size_t)r * DOUT + o];
    }
    const int d0 = t * 4;
    const float4 wv = *(const float4*)&W[(size_t)o * DIN + d0];
    float outv[4] = { wv.x, wv.y, wv.z, wv.w };
    float dwv[4]  = { 0.f, 0.f, 0.f, 0.f };
#pragma unroll
    for (int j = 0; j < TOPKK; ++j) {
        const int p = gidx[j];
#pragma unroll
        for (int dd = 0; dd < 4; ++dd) {
            const float4 da = *(const float4*)&ldown[(size_t)p * DIN * RR + (size_t)(d0 + dd) * RR];
            const float4 db = *(const float4*)&ldown[(size_t)p * DIN * RR + (size_t)(d0 + dd) * RR + 4];
            dwv[dd] += da.x * c[j][0] + da.y * c[j][1] + da.z * c[j][2] + da.w * c[j][3]
                     + db.x * c[j][4] + db.y * c[j][5] + db.z * c[j][6] + db.w * c[j][7];
        }
    }
    bf16x4 b0 = { (__bf16)outv[0], (__bf16)outv[1], (__bf16)outv[2], (__bf16)outv[3] };
    bf16x4 b1 = { (__bf16)(outv[0] + dwv[0]), (__bf16)(outv[1] + dwv[1]),
                  (__bf16)(outv[2] + dwv[2]), (__bf16)(outv[3] + dwv[3]) };
    *(bf16x4*)&Wb0[(size_t)o * DIN + d0] = b0;
    *(bf16x4*)&Wb1[(size_t)o * DIN + d0] = b1;
}

// ---------------- K4: 128x128 bf16 MFMA GEMM (B^T layout) ----------------
// C[m][n] = sum_k A[m][k] * Bt[n][k];  Bt = Wb0 for tm<64, Wb1 for tm>=64.
__global__ __launch_bounds__(256) void k4_gemm(const __bf16* __restrict__ A,
                                               const __bf16* __restrict__ B0,
                                               const __bf16* __restrict__ B1,
                                               float* __restrict__ C) {
    __shared__ ushort As[128 * 64];
    __shared__ ushort Bs[128 * 64];
    const int tn = blockIdx.x;   // 0..7
    const int tm = blockIdx.y;   // 0..127
    const __bf16* __restrict__ Bt = (tm >= 64) ? B1 : B0;
    const int lane = threadIdx.x & 63;
    const int wid  = threadIdx.x >> 6;
    const int wm = wid >> 1, wn = wid & 1;

    // staging geometry: chunk c = wid*4+i covers LDS rows c*8..c*8+7, full BK=64.
    // lane -> row c*8 + (lane>>3), 16B k-chunk (lane&7); pre-swizzle global source
    // so that logical chunk lk = (lane&7) ^ (row&7) lands at linear LDS slot.
    const int lr = lane >> 3;
    const int lk = (lane & 7) ^ lr;

    f32x4 acc[4][4];
#pragma unroll
    for (int i = 0; i < 4; ++i)
#pragma unroll
        for (int j = 0; j < 4; ++j) acc[i][j] = (f32x4){0.f, 0.f, 0.f, 0.f};

    const size_t abase = (size_t)tm * 128 * 1024;
    const size_t bbase = (size_t)tn * 128 * 1024;

    auto stage = [&](int kt) {
#pragma unroll
        for (int i = 0; i < 4; ++i) {
            const int c   = wid * 4 + i;
            const int row = c * 8 + lr;
            const __bf16* ga = A  + abase + (size_t)row * 1024 + (size_t)kt * 64 + lk * 8;
            const __bf16* gb = Bt + bbase + (size_t)row * 1024 + (size_t)kt * 64 + lk * 8;
            __builtin_amdgcn_global_load_lds((const __attribute__((address_space(1))) void*)ga,
                                             (__attribute__((address_space(3))) void*)&As[c * 512],
                                             16, 0, 0);
            __builtin_amdgcn_global_load_lds((const __attribute__((address_space(1))) void*)gb,
                                             (__attribute__((address_space(3))) void*)&Bs[c * 512],
                                             16, 0, 0);
        }
    };

    stage(0);
#pragma unroll 1
    for (int kt = 0; kt < 16; ++kt) {
        __syncthreads();   // compiler emits vmcnt(0) drain before barrier
#pragma unroll
        for (int ks = 0; ks < 2; ++ks) {
            bf16x8 af[4], bfr[4];
            const int chb = (ks * 4 + (lane >> 4)) ^ (lane & 7);  // swizzled 16B chunk
#pragma unroll
            for (int mi = 0; mi < 4; ++mi) {
                const int row = wm * 64 + mi * 16 + (lane & 15);
                af[mi] = *(const bf16x8*)&As[row * 64 + chb * 8];
            }
#pragma unroll
            for (int ni = 0; ni < 4; ++ni) {
                const int row = wn * 64 + ni * 16 + (lane & 15);
                bfr[ni] = *(const bf16x8*)&Bs[row * 64 + chb * 8];
            }
#pragma unroll
            for (int mi = 0; mi < 4; ++mi)
#pragma unroll
                for (int ni = 0; ni < 4; ++ni)
                    acc[mi][ni] = __builtin_amdgcn_mfma_f32_16x16x32_bf16(
                        af[mi], bfr[ni], acc[mi][ni], 0, 0, 0);
        }
        __syncthreads();
        if (kt < 15) stage(kt + 1);
    }

    // epilogue: D col = lane&15, row = (lane>>4)*4 + r
#pragma unroll
    for (int mi = 0; mi < 4; ++mi) {
#pragma unroll
        for (int r = 0; r < 4; ++r) {
            const int grow = tm * 128 + wm * 64 + mi * 16 + (lane >> 4) * 4 + r;
            float* cp = C + (size_t)grow * 1024 + tn * 128 + wn * 64 + (lane & 15);
#pragma unroll
            for (int ni = 0; ni < 4; ++ni) cp[ni * 16] = acc[mi][ni][r];
        }
    }
}

extern "C" void kernel_launch(void* const* d_in, const int* in_sizes, int n_in,
                              void* d_out, int out_size, void* d_ws, size_t ws_size,
                              hipStream_t stream) {
    const float* in     = (const float*)d_in[0];
    const float* W      = (const float*)d_in[1];
    const float* ldown  = (const float*)d_in[2];
    const float* lup    = (const float*)d_in[3];
    const float* lroute = (const float*)d_in[4];
    const int*   taskid = (const int*)d_in[5];
    float* out = (float*)d_out;

    // workspace carve (needs ~37.6 MB)
    __bf16* inB   = (__bf16*)d_ws;                              // 16384*1024*2 B
    __bf16* Wb0   = inB + (size_t)MROWS * DIN;                  // 2 MB
    __bf16* Wb1   = Wb0 + (size_t)DOUT * DIN;                   // 2 MB
    float*  colsum= (float*)(Wb1 + (size_t)DOUT * DIN);         // 4 KB
    float*  gate  = colsum + DIN;
    int*    gidx  = (int*)(gate + TOPKK);

    hipMemsetAsync(colsum, 0, DIN * sizeof(float), stream);
    k1_colsum_cvt<<<512, 256, 0, stream>>>(in, inB, colsum);
    k2_gate<<<1, 64, 0, stream>>>(colsum, lroute, taskid, gate, gidx);
    k3_weights<<<1024, 256, 0, stream>>>(W, ldown, lup, gate, gidx, Wb0, Wb1);
    k4_gemm<<<dim3(8, 128), 256, 0, stream>>>(inB, Wb0, Wb1, out);
}